// Round 1
// baseline (1523.671 us; speedup 1.0000x reference)
//
#include <hip/hip_runtime.h>
#include <hip/hip_bf16.h>

#define VOCAB 50257
#define EMBED 256
#define HIDDEN 128
#define G4 512          // 4*HIDDEN, gate order: i | f | g(tanh) | o
#define BATCH 128
#define SEQ 1024

typedef float f32x4 __attribute__((ext_vector_type(4)));

// ---------------------------------------------------------------------------
// Kernel 1: table[m][n] = dot(emb[m,:], W_ih[n,:]) + b_ih[n] + b_hh[n]
// f32 tiled GEMM (NT: both operands row-contiguous along K).
// BM=128, BN=64, BK=32, 256 threads, 8x4 register tile per thread.
// ---------------------------------------------------------------------------
#define K1_BM 128
#define K1_BN 64
#define K1_BK 32

__global__ __launch_bounds__(256)
void table_gemm(const float* __restrict__ emb, const float* __restrict__ Wih,
                const float* __restrict__ bih, const float* __restrict__ bhh,
                float* __restrict__ table) {
    // padded leading dims: keep 16B alignment (132*4, 68*4 are 16B multiples)
    __shared__ __align__(16) float As[K1_BK][K1_BM + 4];
    __shared__ __align__(16) float Bs[K1_BK][K1_BN + 4];

    const int nTiles = G4 / K1_BN;            // 8 (n fastest-varying -> A-panel L2 reuse)
    const int mt = blockIdx.x / nTiles;
    const int nt = blockIdx.x % nTiles;
    const int m0 = mt * K1_BM, n0 = nt * K1_BN;
    const int tid  = threadIdx.x;
    const int tm   = tid & 15;                // 16 m-subtiles of 8 rows
    const int tn   = tid >> 4;                // 16 n-subtiles of 4 cols
    const int lrow = tid >> 3;                // 0..31 (staging)
    const int lk   = (tid & 7) << 2;          // 0,4,...,28 (staging k-chunk)

    float acc[8][4];
#pragma unroll
    for (int i = 0; i < 8; ++i)
#pragma unroll
        for (int j = 0; j < 4; ++j) acc[i][j] = 0.f;

    for (int k0 = 0; k0 < EMBED; k0 += K1_BK) {
        __syncthreads();   // protect LDS from previous iteration's readers
        // stage A: 128 rows x 32 k (transposed to As[k][m]); coalesced f32x4 loads
#pragma unroll
        for (int p = 0; p < 4; ++p) {
            int m  = m0 + p * 32 + lrow;
            int ms = m < VOCAB ? m : VOCAB - 1;          // clamp tail reads
            f32x4 a = *(const f32x4*)(emb + (size_t)ms * EMBED + k0 + lk);
            As[lk + 0][p * 32 + lrow] = a[0];
            As[lk + 1][p * 32 + lrow] = a[1];
            As[lk + 2][p * 32 + lrow] = a[2];
            As[lk + 3][p * 32 + lrow] = a[3];
        }
        // stage B: 64 rows x 32 k
#pragma unroll
        for (int p = 0; p < 2; ++p) {
            int n = n0 + p * 32 + lrow;
            f32x4 b = *(const f32x4*)(Wih + (size_t)n * EMBED + k0 + lk);
            Bs[lk + 0][p * 32 + lrow] = b[0];
            Bs[lk + 1][p * 32 + lrow] = b[1];
            Bs[lk + 2][p * 32 + lrow] = b[2];
            Bs[lk + 3][p * 32 + lrow] = b[3];
        }
        __syncthreads();
#pragma unroll
        for (int k = 0; k < K1_BK; ++k) {
            f32x4 b4   = *(const f32x4*)&Bs[k][tn * 4];
            f32x4 a4lo = *(const f32x4*)&As[k][tm * 8];
            f32x4 a4hi = *(const f32x4*)&As[k][tm * 8 + 4];
#pragma unroll
            for (int i = 0; i < 4; ++i)
#pragma unroll
                for (int j = 0; j < 4; ++j) {
                    acc[i][j]     += a4lo[i] * b4[j];
                    acc[i + 4][j] += a4hi[i] * b4[j];
                }
        }
    }

    const int nbase = n0 + tn * 4;
    float bias0 = bih[nbase + 0] + bhh[nbase + 0];
    float bias1 = bih[nbase + 1] + bhh[nbase + 1];
    float bias2 = bih[nbase + 2] + bhh[nbase + 2];
    float bias3 = bih[nbase + 3] + bhh[nbase + 3];
#pragma unroll
    for (int i = 0; i < 8; ++i) {
        int m = m0 + tm * 8 + i;
        if (m < VOCAB) {
            f32x4 o;
            o[0] = acc[i][0] + bias0;
            o[1] = acc[i][1] + bias1;
            o[2] = acc[i][2] + bias2;
            o[3] = acc[i][3] + bias3;
            *(f32x4*)(table + (size_t)m * G4 + nbase) = o;
        }
    }
}

// ---------------------------------------------------------------------------
// Kernel 2: sequential LSTM. One workgroup per batch row, 512 threads.
// Thread g owns gate row g: W_hh[g,0:128] lives in 32 f32x4 registers.
// h broadcast via LDS (same-address reads = bank broadcast).
// xg gathered from vocab table with 2-step-ahead prefetch.
// Fused final linear head.
// ---------------------------------------------------------------------------
__global__ __launch_bounds__(512)
void lstm_seq(const int* __restrict__ x, const float* __restrict__ table,
              const float* __restrict__ Whh,
              const float* __restrict__ Wfc, const float* __restrict__ bfc,
              float* __restrict__ out) {
    __shared__ __align__(16) float h_s[HIDDEN];
    __shared__ float act[G4];
    __shared__ int   toks[SEQ];

    const int b = blockIdx.x;
    const int g = threadIdx.x;          // 0..511 == gate row index

    // preload this row's tokens (coalesced, 2 per thread)
    for (int i = g; i < SEQ; i += 512) toks[i] = x[b * SEQ + i];

    // W_hh row g -> registers (static-indexed => stays in VGPRs)
    f32x4 wv[32];
#pragma unroll
    for (int k = 0; k < 32; ++k)
        wv[k] = *(const f32x4*)(Whh + (size_t)g * HIDDEN + 4 * k);

    if (g < HIDDEN) h_s[g] = 0.f;
    float c = 0.f;
    __syncthreads();

    // 2-deep xg prefetch pipeline
    float xg_cur = table[(size_t)toks[0] * G4 + g];
    float xg_nxt = table[(size_t)toks[1] * G4 + g];

    for (int t = 0; t < SEQ; ++t) {
        // issue prefetch for t+2 early (wraps harmlessly at the tail)
        int   tk2   = toks[(t + 2) & (SEQ - 1)];
        float xg_n2 = table[(size_t)tk2 * G4 + g];

        // matvec: pre = xg + dot(W_hh[g,:], h)
        const f32x4* h4 = (const f32x4*)h_s;
        f32x4 s0 = {0.f, 0.f, 0.f, 0.f}, s1 = {0.f, 0.f, 0.f, 0.f};
        f32x4 s2 = {0.f, 0.f, 0.f, 0.f}, s3 = {0.f, 0.f, 0.f, 0.f};
#pragma unroll
        for (int k = 0; k < 32; k += 4) {
            s0 += wv[k + 0] * h4[k + 0];
            s1 += wv[k + 1] * h4[k + 1];
            s2 += wv[k + 2] * h4[k + 2];
            s3 += wv[k + 3] * h4[k + 3];
        }
        f32x4 ss = (s0 + s1) + (s2 + s3);
        float pre = xg_cur + ((ss[0] + ss[1]) + (ss[2] + ss[3]));

        // activation (branch is wave-uniform: g>>7 constant per wave)
        float a;
        if ((g >> 7) == 2) {                    // candidate gate: tanh
            float e = __expf(2.f * pre);
            a = 1.f - 2.f / (e + 1.f);          // inf-safe both directions
        } else {                                // i, f, o: sigmoid
            a = 1.f / (1.f + __expf(-pre));
        }
        act[g] = a;
        __syncthreads();

        if (g < HIDDEN) {                       // waves 0-1: cell/hidden update
            float ig = act[g], fg = act[g + 128];
            float cg = act[g + 256], og = act[g + 384];
            c = fg * c + ig * cg;
            float e  = __expf(2.f * c);
            float th = 1.f - 2.f / (e + 1.f);
            h_s[g] = og * th;
        }
        __syncthreads();

        xg_cur = xg_nxt;
        xg_nxt = xg_n2;
    }

    // fused head: out[b][cls] = dot(h_T, W_fc[cls,:]) + b_fc[cls]
    if (g < 2) {
        const f32x4* wf = (const f32x4*)(Wfc + g * HIDDEN);
        const f32x4* h4 = (const f32x4*)h_s;
        f32x4 s = {0.f, 0.f, 0.f, 0.f};
#pragma unroll
        for (int k = 0; k < 32; ++k) s += wf[k] * h4[k];
        out[b * 2 + g] = bfc[g] + ((s[0] + s[1]) + (s[2] + s[3]));
    }
}

extern "C" void kernel_launch(void* const* d_in, const int* in_sizes, int n_in,
                              void* d_out, int out_size, void* d_ws, size_t ws_size,
                              hipStream_t stream) {
    (void)in_sizes; (void)n_in; (void)out_size; (void)ws_size;
    const int*   x   = (const int*)d_in[0];
    const float* emb = (const float*)d_in[1];
    const float* Wih = (const float*)d_in[2];
    const float* Whh = (const float*)d_in[3];
    const float* bih = (const float*)d_in[4];
    const float* bhh = (const float*)d_in[5];
    const float* Wfc = (const float*)d_in[6];
    const float* bfc = (const float*)d_in[7];
    float* out   = (float*)d_out;
    float* table = (float*)d_ws;    // 50257*512*4 B = 98.2 MB scratch

    const int mTiles = (VOCAB + K1_BM - 1) / K1_BM;   // 393
    const int nTiles = G4 / K1_BN;                    // 8
    table_gemm<<<dim3(mTiles * nTiles), 256, 0, stream>>>(emb, Wih, bih, bhh, table);
    lstm_seq<<<dim3(BATCH), 512, 0, stream>>>(x, table, Whh, Wfc, bfc, out);
}

// Round 2
// 932.686 us; speedup vs baseline: 1.6336x; 1.6336x over previous
//
#include <hip/hip_runtime.h>
#include <hip/hip_bf16.h>

#define VOCAB 50257
#define EMBED 256
#define HIDDEN 128
#define G4 512          // 4*HIDDEN, gate order: i | f | g(tanh) | o
#define BATCH 128
#define SEQ 1024

typedef float f32x4 __attribute__((ext_vector_type(4)));

// DPP quad-permute cross-lane ops (VALU pipe -- must NOT use __shfl_xor here,
// which may lower to ds_bpermute and compete with the h reads on the LDS pipe).
__device__ __forceinline__ float dpp_xor1(float x) {   // lane ^ 1 within quad
    return __int_as_float(__builtin_amdgcn_update_dpp(
        0, __float_as_int(x), 0xB1 /*quad_perm(1,0,3,2)*/, 0xF, 0xF, true));
}
__device__ __forceinline__ float dpp_xor2(float x) {   // lane ^ 2 within quad
    return __int_as_float(__builtin_amdgcn_update_dpp(
        0, __float_as_int(x), 0x4E /*quad_perm(2,3,0,1)*/, 0xF, 0xF, true));
}

// ---------------------------------------------------------------------------
// Kernel 1: table[m][n] = dot(emb[m,:], W_ih[n,:]) + b_ih[n] + b_hh[n]
// (unchanged from round 1: ~190 us, not the bottleneck yet)
// ---------------------------------------------------------------------------
#define K1_BM 128
#define K1_BN 64
#define K1_BK 32

__global__ __launch_bounds__(256)
void table_gemm(const float* __restrict__ emb, const float* __restrict__ Wih,
                const float* __restrict__ bih, const float* __restrict__ bhh,
                float* __restrict__ table) {
    __shared__ __align__(16) float As[K1_BK][K1_BM + 4];
    __shared__ __align__(16) float Bs[K1_BK][K1_BN + 4];

    const int nTiles = G4 / K1_BN;            // 8
    const int mt = blockIdx.x / nTiles;
    const int nt = blockIdx.x % nTiles;
    const int m0 = mt * K1_BM, n0 = nt * K1_BN;
    const int tid  = threadIdx.x;
    const int tm   = tid & 15;
    const int tn   = tid >> 4;
    const int lrow = tid >> 3;
    const int lk   = (tid & 7) << 2;

    float acc[8][4];
#pragma unroll
    for (int i = 0; i < 8; ++i)
#pragma unroll
        for (int j = 0; j < 4; ++j) acc[i][j] = 0.f;

    for (int k0 = 0; k0 < EMBED; k0 += K1_BK) {
        __syncthreads();
#pragma unroll
        for (int p = 0; p < 4; ++p) {
            int m  = m0 + p * 32 + lrow;
            int ms = m < VOCAB ? m : VOCAB - 1;
            f32x4 a = *(const f32x4*)(emb + (size_t)ms * EMBED + k0 + lk);
            As[lk + 0][p * 32 + lrow] = a[0];
            As[lk + 1][p * 32 + lrow] = a[1];
            As[lk + 2][p * 32 + lrow] = a[2];
            As[lk + 3][p * 32 + lrow] = a[3];
        }
#pragma unroll
        for (int p = 0; p < 2; ++p) {
            int n = n0 + p * 32 + lrow;
            f32x4 b = *(const f32x4*)(Wih + (size_t)n * EMBED + k0 + lk);
            Bs[lk + 0][p * 32 + lrow] = b[0];
            Bs[lk + 1][p * 32 + lrow] = b[1];
            Bs[lk + 2][p * 32 + lrow] = b[2];
            Bs[lk + 3][p * 32 + lrow] = b[3];
        }
        __syncthreads();
#pragma unroll
        for (int k = 0; k < K1_BK; ++k) {
            f32x4 b4   = *(const f32x4*)&Bs[k][tn * 4];
            f32x4 a4lo = *(const f32x4*)&As[k][tm * 8];
            f32x4 a4hi = *(const f32x4*)&As[k][tm * 8 + 4];
#pragma unroll
            for (int i = 0; i < 4; ++i)
#pragma unroll
                for (int j = 0; j < 4; ++j) {
                    acc[i][j]     += a4lo[i] * b4[j];
                    acc[i + 4][j] += a4hi[i] * b4[j];
                }
        }
    }

    const int nbase = n0 + tn * 4;
    float bias0 = bih[nbase + 0] + bhh[nbase + 0];
    float bias1 = bih[nbase + 1] + bhh[nbase + 1];
    float bias2 = bih[nbase + 2] + bhh[nbase + 2];
    float bias3 = bih[nbase + 3] + bhh[nbase + 3];
#pragma unroll
    for (int i = 0; i < 8; ++i) {
        int m = m0 + tm * 8 + i;
        if (m < VOCAB) {
            f32x4 o;
            o[0] = acc[i][0] + bias0;
            o[1] = acc[i][1] + bias1;
            o[2] = acc[i][2] + bias2;
            o[3] = acc[i][3] + bias3;
            *(f32x4*)(table + (size_t)m * G4 + nbase) = o;
        }
    }
}

// ---------------------------------------------------------------------------
// Kernel 2: sequential LSTM, quad-k-split matvec.
//   quad Q (tid>>2) = hidden unit; lane i (tid&3) owns k-chunk [32i,32i+32)
//   for all 4 gate rows {Q, Q+128, Q+256, Q+384}. Weights in 128 VGPRs.
//   h reads: 8 ds_read_b128/thread, XOR-permuted chunk order (j^2i) so the
//   4 quad positions hit disjoint bank-quads (16-way same-addr broadcast,
//   conflict-free). Quad reduce via DPP. One barrier/step (h double-buffer).
// ---------------------------------------------------------------------------
__global__ __launch_bounds__(512, 2)
void lstm_seq(const int* __restrict__ x, const float* __restrict__ table,
              const float* __restrict__ Whh,
              const float* __restrict__ Wfc, const float* __restrict__ bfc,
              float* __restrict__ out) {
    __shared__ __align__(16) float h_s[2][HIDDEN];
    __shared__ int toks[SEQ];

    const int b   = blockIdx.x;
    const int tid = threadIdx.x;
    const int i4  = tid & 3;     // k-chunk slot / xg gate index
    const int Q   = tid >> 2;    // hidden unit 0..127

    for (int t = tid; t < SEQ; t += 512) toks[t] = x[b * SEQ + t];

    // W_hh rows {g*128+Q}, k-chunk [32*i4,32*i4+32) in XOR-permuted j order.
    // Load-time permutation => zero runtime cost; sum order is irrelevant.
    f32x4 wv[4][8];
#pragma unroll
    for (int g = 0; g < 4; ++g)
#pragma unroll
        for (int j = 0; j < 8; ++j)
            wv[g][j] = *(const f32x4*)(Whh + (size_t)(g * HIDDEN + Q) * HIDDEN
                                           + 32 * i4 + 4 * (j ^ (2 * i4)));

    if (tid < HIDDEN) h_s[0][tid] = 0.f;
    float c = 0.f;
    const int lane_off = i4 * HIDDEN + Q;   // this lane fetches xg of gate i4
    __syncthreads();

    float xg_cur = table[(size_t)toks[0] * G4 + lane_off];
    float xg_nxt = table[(size_t)toks[1] * G4 + lane_off];

    for (int t = 0; t < SEQ; ++t) {
        // prefetch xg for t+2 (tail wraps harmlessly)
        int   tk2   = toks[(t + 2) & (SEQ - 1)];
        float xg_n2 = table[(size_t)tk2 * G4 + lane_off];

        // h chunk for this lane (XOR-permuted order matches wv)
        const float* hb = h_s[t & 1];
        f32x4 hc[8];
#pragma unroll
        for (int j = 0; j < 8; ++j)
            hc[j] = *(const f32x4*)(hb + 32 * i4 + 4 * (j ^ (2 * i4)));

        // 4 partial dots (one per gate row) over this lane's 32 h values
        f32x4 a0 = {0.f,0.f,0.f,0.f}, a1 = {0.f,0.f,0.f,0.f};
        f32x4 a2 = {0.f,0.f,0.f,0.f}, a3 = {0.f,0.f,0.f,0.f};
#pragma unroll
        for (int j = 0; j < 8; ++j) {
            a0 += wv[0][j] * hc[j];
            a1 += wv[1][j] * hc[j];
            a2 += wv[2][j] * hc[j];
            a3 += wv[3][j] * hc[j];
        }
        float p0 = (a0[0] + a0[1]) + (a0[2] + a0[3]);
        float p1 = (a1[0] + a1[1]) + (a1[2] + a1[3]);
        float p2 = (a2[0] + a2[1]) + (a2[2] + a2[3]);
        float p3 = (a3[0] + a3[1]) + (a3[2] + a3[3]);
        // fold xg in exactly once: lane i4 carries xg of gate row i4
        p0 += (i4 == 0) ? xg_cur : 0.f;
        p1 += (i4 == 1) ? xg_cur : 0.f;
        p2 += (i4 == 2) ? xg_cur : 0.f;
        p3 += (i4 == 3) ? xg_cur : 0.f;

        // quad reduction: 2 butterfly rounds + redistribution, all DPP
        float u0 = p0 + dpp_xor1(p0);
        float u1 = p1 + dpp_xor1(p1);
        float u2 = p2 + dpp_xor1(p2);
        float u3 = p3 + dpp_xor1(p3);
        float v0 = (i4 & 1) ? u2 : u0;     // even lanes track rows {0,1}, odd {2,3}
        float v1 = (i4 & 1) ? u3 : u1;
        float w0 = v0 + dpp_xor2(v0);      // full sums: rows {2*(i4&1), +1}
        float w1 = v1 + dpp_xor2(v1);
        float o0 = dpp_xor1(w0);           // other pair's rows
        float o1 = dpp_xor1(w1);
        float gi = (i4 & 1) ? o0 : w0;     // gate 0 (input)
        float gf = (i4 & 1) ? o1 : w1;     // gate 1 (forget)
        float gg = (i4 & 1) ? w0 : o0;     // gate 2 (candidate, tanh)
        float go = (i4 & 1) ? w1 : o1;     // gate 3 (output)

        // activations + cell update (redundant across the quad: uniform, free)
        float si = __builtin_amdgcn_rcpf(1.f + __expf(-gi));
        float sf = __builtin_amdgcn_rcpf(1.f + __expf(-gf));
        float so = __builtin_amdgcn_rcpf(1.f + __expf(-go));
        float eg = __expf(2.f * gg);
        float tg = 1.f - 2.f * __builtin_amdgcn_rcpf(eg + 1.f);   // tanh
        c = sf * c + si * tg;
        float ec = __expf(2.f * c);
        float tc = 1.f - 2.f * __builtin_amdgcn_rcpf(ec + 1.f);   // tanh(c)
        float h  = so * tc;

        if (i4 == 0) h_s[(t + 1) & 1][Q] = h;   // 16 consecutive banks/wave
        __syncthreads();                         // single barrier per step

        xg_cur = xg_nxt;
        xg_nxt = xg_n2;
    }

    // fused head: h_T ended in buffer (1023+1)&1 == 0
    if (tid < 2) {
        const f32x4* wf = (const f32x4*)(Wfc + tid * HIDDEN);
        const f32x4* h4 = (const f32x4*)h_s[0];
        f32x4 s = {0.f, 0.f, 0.f, 0.f};
#pragma unroll
        for (int k = 0; k < 32; ++k) s += wf[k] * h4[k];
        out[b * 2 + tid] = bfc[tid] + ((s[0] + s[1]) + (s[2] + s[3]));
    }
}

extern "C" void kernel_launch(void* const* d_in, const int* in_sizes, int n_in,
                              void* d_out, int out_size, void* d_ws, size_t ws_size,
                              hipStream_t stream) {
    (void)in_sizes; (void)n_in; (void)out_size; (void)ws_size;
    const int*   x   = (const int*)d_in[0];
    const float* emb = (const float*)d_in[1];
    const float* Wih = (const float*)d_in[2];
    const float* Whh = (const float*)d_in[3];
    const float* bih = (const float*)d_in[4];
    const float* bhh = (const float*)d_in[5];
    const float* Wfc = (const float*)d_in[6];
    const float* bfc = (const float*)d_in[7];
    float* out   = (float*)d_out;
    float* table = (float*)d_ws;    // 50257*512*4 B = 98.2 MB scratch

    const int mTiles = (VOCAB + K1_BM - 1) / K1_BM;   // 393
    const int nTiles = G4 / K1_BN;                    // 8
    table_gemm<<<dim3(mTiles * nTiles), 256, 0, stream>>>(emb, Wih, bih, bhh, table);
    lstm_seq<<<dim3(BATCH), 512, 0, stream>>>(x, table, Whh, Wfc, bfc, out);
}